// Round 16
// baseline (235.335 us; speedup 1.0000x reference)
//
#include <hip/hip_runtime.h>
#include <math.h>

#define TT 2048
#define DD 512
#define HEADS 8
#define DH 64
#define NI 4
#define DI 64
#define KSEL 128

typedef __bf16 bfr;
typedef bfr bf16x8 __attribute__((ext_vector_type(8)));
typedef float f32x4 __attribute__((ext_vector_type(4)));

__device__ __forceinline__ float sigmoidf_(float z) {
    return 1.0f / (1.0f + __expf(-z));
}

__device__ __forceinline__ ushort f2bf(float f) {
    unsigned u = __float_as_uint(f);
    unsigned r = (u + 0x7fffu + ((u >> 16) & 1u)) >> 16;
    return (ushort)r;
}

__device__ __forceinline__ float bf2f(ushort u) {
    return __uint_as_float(((unsigned)u) << 16);
}

// ---------------------------------------------------------------------------
// fp32 64x64 GEMM tile, split-K with register prefetch; atomicAdd combine.
// ---------------------------------------------------------------------------
__device__ __forceinline__ void gemm_tile64_sk(const float* __restrict__ A,
                                               const float* __restrict__ B,
                                               float* __restrict__ C,
                                               int N, int bm, int bn0,
                                               int k0beg, int k0end) {
    __shared__ float Ast[16][64];
    __shared__ float Bs[16][64];
    int tid = threadIdx.x;
    int tx = tid & 15, ty = tid >> 4;
    int ma = tid >> 2, kq = tid & 3;
    int kb_ = tid >> 4, n4 = tid & 15;
    float acc[4][4] = {};
    float4 a_cur = *(const float4*)(A + (size_t)(bm + ma) * 512 + k0beg + kq * 4);
    float4 b_cur = *(const float4*)(B + (size_t)(k0beg + kb_) * N + bn0 + n4 * 4);
    for (int k0 = k0beg; k0 < k0end; k0 += 16) {
        *(float4*)&Bs[kb_][n4 * 4] = b_cur;
        Ast[kq * 4 + 0][ma] = a_cur.x;
        Ast[kq * 4 + 1][ma] = a_cur.y;
        Ast[kq * 4 + 2][ma] = a_cur.z;
        Ast[kq * 4 + 3][ma] = a_cur.w;
        __syncthreads();
        if (k0 + 16 < k0end) {
            a_cur = *(const float4*)(A + (size_t)(bm + ma) * 512 + k0 + 16 + kq * 4);
            b_cur = *(const float4*)(B + (size_t)(k0 + 16 + kb_) * N + bn0 + n4 * 4);
        }
#pragma unroll
        for (int kk = 0; kk < 16; ++kk) {
            float4 a4 = *(const float4*)&Ast[kk][ty * 4];
            float4 b4 = *(const float4*)&Bs[kk][tx * 4];
            float af[4] = {a4.x, a4.y, a4.z, a4.w};
            float bf[4] = {b4.x, b4.y, b4.z, b4.w};
#pragma unroll
            for (int i = 0; i < 4; ++i)
#pragma unroll
                for (int j = 0; j < 4; ++j) acc[i][j] += af[i] * bf[j];
        }
        __syncthreads();
    }
#pragma unroll
    for (int i = 0; i < 4; ++i) {
        int mrow = bm + ty * 4 + i;
#pragma unroll
        for (int j = 0; j < 4; ++j)
            atomicAdd(&C[(size_t)mrow * N + bn0 + tx * 4 + j], acc[i][j]);
    }
}

// ---------------------------------------------------------------------------
// prep: proj32-splitK (320) | castx (1024) | wtrans (1536) | iw (512) = 3392
// ---------------------------------------------------------------------------
__global__ __launch_bounds__(256) void prep_kernel(
    const float* __restrict__ x, const float* __restrict__ Wq,
    const float* __restrict__ Wk, const float* __restrict__ Wv,
    const float* __restrict__ Wvg, const float* __restrict__ Wog,
    const float* __restrict__ Wo, const float* __restrict__ Wiq,
    const float* __restrict__ Wik, const float* __restrict__ Wiw,
    const float* __restrict__ biw, ushort* __restrict__ xb,
    ushort* __restrict__ wtb, float* __restrict__ qib,
    float* __restrict__ kib, float* __restrict__ wsb) {
    int b = blockIdx.x, tid = threadIdx.x;
    if (b < 320) {
        int tp = b >> 1, kh = b & 1;
        int bn = tp % 5, bm = (tp / 5) * 64;
        int k0beg = kh * 256, k0end = k0beg + 256;
        if (bn < 4)
            gemm_tile64_sk(x, Wiq, qib, 256, bm, bn * 64, k0beg, k0end);
        else
            gemm_tile64_sk(x, Wik, kib, 64, bm, 0, k0beg, k0end);
    } else if (b < 1344) {
        int e = (b - 320) * 256 + tid;
        float4 v = ((const float4*)x)[e];
        ushort4 r;
        r.x = f2bf(v.x); r.y = f2bf(v.y); r.z = f2bf(v.z); r.w = f2bf(v.w);
        ((ushort4*)xb)[e] = r;
    } else if (b < 2880) {
        __shared__ float t[32][33];
        int p = b - 1344;
        int mat = p >> 8, tt = p & 255;
        int n0 = (tt & 15) * 32, k0 = (tt >> 4) * 32;
        const float* srcs[6] = {Wq, Wk, Wv, Wvg, Wog, Wo};
        const float* W = srcs[mat];
        ushort* outp = wtb + (size_t)mat * 512 * 512;
        int c = tid & 31, r8 = tid >> 5;
#pragma unroll
        for (int rr = 0; rr < 32; rr += 8)
            t[r8 + rr][c] = W[(size_t)(k0 + r8 + rr) * 512 + n0 + c];
        __syncthreads();
#pragma unroll
        for (int rr = 0; rr < 32; rr += 8)
            outp[(size_t)(n0 + r8 + rr) * 512 + k0 + c] = f2bf(t[c][r8 + rr]);
    } else {
        int lane = tid & 63, wv = tid >> 6;
        int row = (b - 2880) * 4 + wv;
        float a0 = 0.f, a1 = 0.f, a2 = 0.f, a3 = 0.f;
        for (int k = lane; k < DD; k += 64) {
            float xv = x[row * DD + k];
            float4 wv4 = *(const float4*)(Wiw + k * NI);
            a0 += xv * wv4.x; a1 += xv * wv4.y;
            a2 += xv * wv4.z; a3 += xv * wv4.w;
        }
#pragma unroll
        for (int off = 32; off; off >>= 1) {
            a0 += __shfl_down(a0, off);
            a1 += __shfl_down(a1, off);
            a2 += __shfl_down(a2, off);
            a3 += __shfl_down(a3, off);
        }
        if (lane == 0) {
            wsb[row * NI + 0] = sigmoidf_(a0 + biw[0]);
            wsb[row * NI + 1] = sigmoidf_(a1 + biw[1]);
            wsb[row * NI + 2] = sigmoidf_(a2 + biw[2]);
            wsb[row * NI + 3] = sigmoidf_(a3 + biw[3]);
        }
    }
}

// ---------------------------------------------------------------------------
// mid: MFMA projections as 64x64 tiles (blocks 0..1279) | score (1280..1807).
// Small tiles -> 1280 blocks -> ~5 blocks/CU, short critical path per block.
// ---------------------------------------------------------------------------
__global__ __launch_bounds__(256) void mid_kernel(
    const ushort* __restrict__ A, const ushort* __restrict__ BT,
    float* __restrict__ qo, float* __restrict__ ko, float* __restrict__ vo,
    float* __restrict__ vgo, float* __restrict__ ogo,
    const float* __restrict__ bvg, const float* __restrict__ bog,
    const float* __restrict__ qi, const float* __restrict__ ki,
    const float* __restrict__ wsig, const float* __restrict__ idx_bias,
    unsigned* __restrict__ keys) {
    __shared__ union {
        struct {
            __align__(16) ushort As[64][32];
            __align__(16) ushort Bs[64][32];
        } mf;
        struct {
            float As[64][65];
            float Bs[64][65];
        } sc;
    } u;
    int gb = blockIdx.x;
    int tid = threadIdx.x;
    if (gb < 1280) {
        // ------------------ MFMA bf16 projections, 64x64 tile ------------------
        const int K = 512;
        int bn = gb % 40, by = gb / 40;
        int bm0 = by * 64;
        int bt_row = bn * 64;  // row base into concatenated BT
        int w = tid >> 6, lane = tid & 63;
        int wm = (w >> 1) * 32, wn = (w & 1) * 32;
        int quad = lane >> 4, mr = lane & 15;
        f32x4 acc[2][2];
#pragma unroll
        for (int i = 0; i < 2; ++i)
#pragma unroll
            for (int j = 0; j < 2; ++j)
#pragma unroll
                for (int r = 0; r < 4; ++r) acc[i][j][r] = 0.f;
        int rs = tid >> 2, cs = (tid & 3) * 8;
        for (int k0 = 0; k0 < K; k0 += 32) {
            *(float4*)&u.mf.As[rs][cs] =
                *(const float4*)(A + (size_t)(bm0 + rs) * K + k0 + cs);
            *(float4*)&u.mf.Bs[rs][cs] =
                *(const float4*)(BT + (size_t)(bt_row + rs) * K + k0 + cs);
            __syncthreads();
            bf16x8 af[2], bfv[2];
#pragma unroll
            for (int i = 0; i < 2; ++i)
                af[i] = *(const bf16x8*)&u.mf.As[wm + i * 16 + mr][quad * 8];
#pragma unroll
            for (int j = 0; j < 2; ++j)
                bfv[j] = *(const bf16x8*)&u.mf.Bs[wn + j * 16 + mr][quad * 8];
#pragma unroll
            for (int i = 0; i < 2; ++i)
#pragma unroll
                for (int j = 0; j < 2; ++j)
                    acc[i][j] = __builtin_amdgcn_mfma_f32_16x16x32_bf16(
                        af[i], bfv[j], acc[i][j], 0, 0, 0);
            __syncthreads();
        }
        int mat = bn >> 3;
        float* C = mat == 0 ? qo : mat == 1 ? ko : mat == 2 ? vo : mat == 3 ? vgo : ogo;
        const float* bias = mat == 3 ? bvg : mat == 4 ? bog : nullptr;
        int bn0 = (bn & 7) * 64;
#pragma unroll
        for (int i = 0; i < 2; ++i)
#pragma unroll
            for (int j = 0; j < 2; ++j) {
                int col = bn0 + wn + j * 16 + mr;
                float bv = bias ? bias[col] : 0.f;
#pragma unroll
                for (int r = 0; r < 4; ++r) {
                    int row = bm0 + wm + i * 16 + quad * 4 + r;
                    float val = acc[i][j][r];
                    if (bias) val = sigmoidf_(val + bv);
                    C[(size_t)row * 512 + col] = val;
                }
            }
    } else {
        // ------------------ index-score lower-triangle tiles ------------------
        int b = gb - 1280;
        int bq = (int)((sqrtf(8.0f * (float)b + 1.0f) - 1.0f) * 0.5f);
        while ((bq + 1) * (bq + 2) / 2 <= b) ++bq;
        while (bq * (bq + 1) / 2 > b) --bq;
        int bk = b - bq * (bq + 1) / 2;
        int q0 = bq * 64, k0 = bk * 64;
        int tx = tid & 15, ty = tid >> 4;
        float fin[4][4] = {};
#pragma unroll
        for (int i = 0; i < 4; ++i) {
            int e = tid + i * 256;
            int r = e >> 4, c4 = e & 15;
            float4 bv = *(const float4*)(ki + (size_t)(k0 + r) * DI + c4 * 4);
            u.sc.Bs[c4 * 4 + 0][r] = bv.x;
            u.sc.Bs[c4 * 4 + 1][r] = bv.y;
            u.sc.Bs[c4 * 4 + 2][r] = bv.z;
            u.sc.Bs[c4 * 4 + 3][r] = bv.w;
            float4 av = *(const float4*)(qi + (size_t)(q0 + r) * (NI * DI) + c4 * 4);
            u.sc.As[r][c4 * 4 + 0] = av.x;
            u.sc.As[r][c4 * 4 + 1] = av.y;
            u.sc.As[r][c4 * 4 + 2] = av.z;
            u.sc.As[r][c4 * 4 + 3] = av.w;
        }
        __syncthreads();
#pragma unroll
        for (int h = 0; h < NI; ++h) {
            float raw[4][4] = {};
#pragma unroll 8
            for (int kk = 0; kk < 64; ++kk) {
                float a[4], bb[4];
#pragma unroll
                for (int i = 0; i < 4; ++i) a[i] = u.sc.As[ty * 4 + i][kk];
#pragma unroll
                for (int j = 0; j < 4; ++j) bb[j] = u.sc.Bs[kk][tx * 4 + j];
#pragma unroll
                for (int i = 0; i < 4; ++i)
#pragma unroll
                    for (int j = 0; j < 4; ++j) raw[i][j] += a[i] * bb[j];
            }
            float bh = idx_bias[h];
            float w4[4];
#pragma unroll
            for (int i = 0; i < 4; ++i) w4[i] = wsig[(q0 + ty * 4 + i) * NI + h];
#pragma unroll
            for (int i = 0; i < 4; ++i)
#pragma unroll
                for (int j = 0; j < 4; ++j)
                    fin[i][j] += sigmoidf_(raw[i][j] * 0.125f + bh) * w4[i];
            if (h < NI - 1) {
                __syncthreads();
#pragma unroll
                for (int i = 0; i < 4; ++i) {
                    int e = tid + i * 256;
                    int r = e >> 4, c4 = e & 15;
                    float4 av = *(const float4*)(qi + (size_t)(q0 + r) * (NI * DI) +
                                                 (h + 1) * DI + c4 * 4);
                    u.sc.As[r][c4 * 4 + 0] = av.x;
                    u.sc.As[r][c4 * 4 + 1] = av.y;
                    u.sc.As[r][c4 * 4 + 2] = av.z;
                    u.sc.As[r][c4 * 4 + 3] = av.w;
                }
                __syncthreads();
            }
        }
#pragma unroll
        for (int i = 0; i < 4; ++i) {
            int qq = q0 + ty * 4 + i;
#pragma unroll
            for (int j = 0; j < 4; ++j) {
                int kk = k0 + tx * 4 + j;
                unsigned key = 0;
                if (kk <= qq) {
                    unsigned uu = __float_as_uint(fin[i][j]);
                    key = (uu & 0x80000000u) ? ~uu : (uu | 0x80000000u);
                }
                keys[(size_t)qq * TT + kk] = key;
            }
        }
    }
}

// ---------------------------------------------------------------------------
// late: topk (blocks 0..2047) | post vmul+rope (2048..5119).
// ---------------------------------------------------------------------------
__global__ __launch_bounds__(256) void late_kernel(
    const unsigned* __restrict__ keys, int* __restrict__ indices,
    int* __restrict__ counts, const float* __restrict__ vb,
    const float* __restrict__ vgb, ushort* __restrict__ v16,
    float* __restrict__ q, const float* __restrict__ k,
    ushort* __restrict__ k16) {
    __shared__ unsigned ks_[TT];
    __shared__ unsigned hist[256];
    __shared__ unsigned wtot[4];
    __shared__ unsigned s_prefix, s_above;
    __shared__ int eqlist[256];
    __shared__ unsigned eqcount, outpos;
    int gb = blockIdx.x;
    int tid = threadIdx.x;
    if (gb >= 2048) {
        int b = gb - 2048;
        if (b < 1024) {
            int e = b * 256 + tid;
            float4 v = ((const float4*)vb)[e];
            float4 g = ((const float4*)vgb)[e];
            ushort4 r;
            r.x = f2bf(v.x * g.x); r.y = f2bf(v.y * g.y);
            r.z = f2bf(v.z * g.z); r.w = f2bf(v.w * g.w);
            ((ushort4*)v16)[e] = r;
        } else {
            int i = (b - 1024) * 256 + tid;
            int j = i & 31;
            int h = (i >> 5) & 7;
            int t = i >> 8;
            const float L2_10000 = 13.287712379549449f;
            float inv = exp2f(-(float)j * (1.0f / 32.0f) * L2_10000);
            float ang = (float)t * inv;
            float c = cosf(ang), s = sinf(ang);
            int base = t * DD + h * DH;
            float q1 = q[base + j], q2 = q[base + j + 32];
            q[base + j] = q1 * c - q2 * s;
            q[base + j + 32] = q2 * c + q1 * s;
            float k1 = k[base + j], k2 = k[base + j + 32];
            k16[base + j] = f2bf(k1 * c - k2 * s);
            k16[base + j + 32] = f2bf(k2 * c + k1 * s);
        }
        return;
    }
    int qrow = gb;
    int lane = tid & 63, wv = tid >> 6;
    int n = qrow + 1;
    if (n <= KSEL) {
        if (tid < n) indices[qrow * KSEL + tid] = tid;
        if (tid == 0) counts[qrow] = n;
        return;
    }
    if (tid == 0) counts[qrow] = KSEL;
    const unsigned* krow = keys + (size_t)qrow * TT;
    for (int k_ = tid; k_ < n; k_ += 256) ks_[k_] = krow[k_];
    __syncthreads();
    unsigned prefix = 0;
    int remaining = KSEL;
    for (int level = 24; level >= 0; level -= 8) {
        hist[tid] = 0;
        __syncthreads();
        for (int k_ = tid; k_ < n; k_ += 256) {
            unsigned key = ks_[k_];
            bool match = ((unsigned long long)key >> (level + 8)) == (unsigned long long)prefix;
            if (match) atomicAdd(&hist[(key >> level) & 255], 1u);
        }
        __syncthreads();
        unsigned v = hist[tid];
#pragma unroll
        for (int off = 1; off < 64; off <<= 1) {
            unsigned t = __shfl_down(v, off);
            if (lane + off < 64) v += t;
        }
        if (lane == 0) wtot[wv] = v;
        __syncthreads();
        unsigned add = 0;
#pragma unroll
        for (int uu = 1; uu < 4; ++uu)
            if (wv + uu < 4) add += wtot[wv + uu];
        v += add;
        hist[tid] = v;
        __syncthreads();
        if (hist[tid] >= (unsigned)remaining &&
            (tid == 255 || hist[tid + 1] < (unsigned)remaining)) {
            s_prefix = (prefix << 8) | (unsigned)tid;
            s_above = (tid == 255) ? 0u : hist[tid + 1];
        }
        __syncthreads();
        prefix = s_prefix;
        remaining -= (int)s_above;
        __syncthreads();
    }
    if (tid == 0) { eqcount = 0; outpos = 0; }
    __syncthreads();
    int outbase = qrow * KSEL;
    for (int k_ = tid; k_ < n; k_ += 256) {
        unsigned key = ks_[k_];
        if (key > prefix) {
            unsigned p = atomicAdd(&outpos, 1u);
            indices[outbase + p] = k_;
        } else if (key == prefix) {
            unsigned e = atomicAdd(&eqcount, 1u);
            if (e < 256) eqlist[e] = k_;
        }
    }
    __syncthreads();
    if (tid == 0) {
        int r = remaining;
        int E = (int)eqcount;
        if (E > 256) E = 256;
        if (r > E) r = E;
        int pos = (int)outpos;
        for (int t = 0; t < r; ++t) {
            int best = 0x7fffffff, bj = -1;
            for (int j = 0; j < E; ++j) {
                int vv = eqlist[j];
                if (vv < best) { best = vv; bj = j; }
            }
            eqlist[bj] = 0x7fffffff;
            indices[outbase + pos + t] = best;
        }
    }
}

// ---------------------------------------------------------------------------
// Sparse attention: grid (TT,2), wave w owns head blockIdx.y*4+w.
// ---------------------------------------------------------------------------
__global__ __launch_bounds__(256) void attn_kernel(
    const float* __restrict__ q, const ushort* __restrict__ k16,
    const ushort* __restrict__ v16, const float* __restrict__ og,
    const int* __restrict__ indices, const int* __restrict__ counts,
    ushort* __restrict__ out) {
    __shared__ int idx[KSEL];
    __shared__ ushort kw[4][32 * 68];
    __shared__ float qv[4][DH];
    __shared__ float pw[4][KSEL];
    int qrow = blockIdx.x;
    int tid = threadIdx.x;
    int lane = tid & 63, w = tid >> 6;
    int cnt = counts[qrow];
    if (tid < KSEL) idx[tid] = (tid < cnt) ? indices[qrow * KSEL + tid] : 0;
    __syncthreads();
    ushort* kws = kw[w];
    float* qvs = qv[w];
    float* pps = pw[w];
    int h = blockIdx.y * 4 + w;
    int hb = h * DH;
    qvs[lane] = q[qrow * DD + hb + lane];
    int j2 = lane & 31, half = lane >> 5;
    int r4 = lane >> 4, cs = (lane & 15) * 4;
    float sc[4];
#pragma unroll
    for (int c = 0; c < 4; ++c) {
#pragma unroll
        for (int it = 0; it < 8; ++it) {
            int r = it * 4 + r4;
            int row = idx[c * 32 + r];
            *(ushort4*)&kws[r * 68 + cs] =
                *(const ushort4*)(k16 + (size_t)row * DD + hb + cs);
        }
        float acc0 = 0.f, acc1 = 0.f;
        const ushort* kr = kws + j2 * 68 + half * 32;
        const float* qr = qvs + half * 32;
#pragma unroll
        for (int dd = 0; dd < 8; dd += 2) {
            ushort4 ka = *(const ushort4*)&kr[dd * 4];
            ushort4 kb_ = *(const ushort4*)&kr[dd * 4 + 4];
            acc0 += bf2f(ka.x) * qr[dd * 4 + 0] + bf2f(ka.y) * qr[dd * 4 + 1] +
                    bf2f(ka.z) * qr[dd * 4 + 2] + bf2f(ka.w) * qr[dd * 4 + 3];
            acc1 += bf2f(kb_.x) * qr[dd * 4 + 4] + bf2f(kb_.y) * qr[dd * 4 + 5] +
                    bf2f(kb_.z) * qr[dd * 4 + 6] + bf2f(kb_.w) * qr[dd * 4 + 7];
        }
        float acc = acc0 + acc1;
        acc += __shfl_xor(acc, 32);
        int j = c * 32 + j2;
        sc[c] = (j < cnt) ? acc * 0.125f : -1e30f;
    }
    float m = fmaxf(fmaxf(sc[0], sc[1]), fmaxf(sc[2], sc[3]));
#pragma unroll
    for (int off = 16; off; off >>= 1) m = fmaxf(m, __shfl_xor(m, off));
    float pc[4], sum = 0.f;
#pragma unroll
    for (int c = 0; c < 4; ++c) {
        pc[c] = __expf(sc[c] - m);
        sum += pc[c];
    }
#pragma unroll
    for (int off = 16; off; off >>= 1) sum += __shfl_xor(sum, off);
    float inv = 1.0f / sum;
    if (half == 0) {
#pragma unroll
        for (int c = 0; c < 4; ++c) pps[c * 32 + j2] = pc[c] * inv;
    }
    int dgroup = lane & 15, g = lane >> 4;
    int db = dgroup * 4;
    float a0 = 0.f, a1 = 0.f, a2 = 0.f, a3 = 0.f;
    float b0 = 0.f, b1 = 0.f, b2 = 0.f, b3 = 0.f;
#pragma unroll 8
    for (int t = 0; t < 32; t += 2) {
        int jA = g + 4 * t;
        int jB = g + 4 * t + 4;
        int rowA = idx[jA];
        int rowB = idx[jB];
        float pA = pps[jA], pB = pps[jB];
        ushort4 va = *(const ushort4*)(v16 + (size_t)rowA * DD + hb + db);
        ushort4 vb = *(const ushort4*)(v16 + (size_t)rowB * DD + hb + db);
        a0 += pA * bf2f(va.x); a1 += pA * bf2f(va.y);
        a2 += pA * bf2f(va.z); a3 += pA * bf2f(va.w);
        b0 += pB * bf2f(vb.x); b1 += pB * bf2f(vb.y);
        b2 += pB * bf2f(vb.z); b3 += pB * bf2f(vb.w);
    }
    a0 += b0; a1 += b1; a2 += b2; a3 += b3;
    a0 += __shfl_xor(a0, 16); a0 += __shfl_xor(a0, 32);
    a1 += __shfl_xor(a1, 16); a1 += __shfl_xor(a1, 32);
    a2 += __shfl_xor(a2, 16); a2 += __shfl_xor(a2, 32);
    a3 += __shfl_xor(a3, 16); a3 += __shfl_xor(a3, 32);
    if (g == 0) {
        int o = qrow * DD + hb + db;
        float4 gg = *(const float4*)(og + o);
        ushort4 r;
        r.x = f2bf(a0 * gg.x);
        r.y = f2bf(a1 * gg.y);
        r.z = f2bf(a2 * gg.z);
        r.w = f2bf(a3 * gg.w);
        *(ushort4*)(out + o) = r;
    }
}

// ---------------------------------------------------------------------------
// Wo MFMA GEMM, 64x64 tile (4 waves x 2x2 fragments) -> 256 blocks.
// ---------------------------------------------------------------------------
__global__ __launch_bounds__(256) void wo64_kernel(
    const ushort* __restrict__ A, const ushort* __restrict__ BT,
    float* __restrict__ C) {
    __shared__ __align__(16) ushort As[64][32];
    __shared__ __align__(16) ushort Bs[64][32];
    const int K = 512;
    int tid = threadIdx.x;
    int bm0 = blockIdx.y * 64, bn0 = blockIdx.x * 64;
    int w = tid >> 6, lane = tid & 63;
    int wm = (w >> 1) * 32, wn = (w & 1) * 32;
    int quad = lane >> 4, mr = lane & 15;
    f32x4 acc[2][2];
#pragma unroll
    for (int i = 0; i < 2; ++i)
#pragma unroll
        for (int j = 0; j < 2; ++j)
#pragma unroll
            for (int r = 0; r < 4; ++r) acc[i][j][r] = 0.f;
    int rs = tid >> 2, cs = (tid & 3) * 8;
    for (int k0 = 0; k0 < K; k0 += 32) {
        *(float4*)&As[rs][cs] = *(const float4*)(A + (size_t)(bm0 + rs) * K + k0 + cs);
        *(float4*)&Bs[rs][cs] = *(const float4*)(BT + (size_t)(bn0 + rs) * K + k0 + cs);
        __syncthreads();
        bf16x8 af[2], bfv[2];
#pragma unroll
        for (int i = 0; i < 2; ++i)
            af[i] = *(const bf16x8*)&As[wm + i * 16 + mr][quad * 8];
#pragma unroll
        for (int j = 0; j < 2; ++j)
            bfv[j] = *(const bf16x8*)&Bs[wn + j * 16 + mr][quad * 8];
#pragma unroll
        for (int i = 0; i < 2; ++i)
#pragma unroll
            for (int j = 0; j < 2; ++j)
                acc[i][j] = __builtin_amdgcn_mfma_f32_16x16x32_bf16(
                    af[i], bfv[j], acc[i][j], 0, 0, 0);
        __syncthreads();
    }
#pragma unroll
    for (int i = 0; i < 2; ++i)
#pragma unroll
        for (int j = 0; j < 2; ++j) {
            int col = bn0 + wn + j * 16 + mr;
#pragma unroll
            for (int r = 0; r < 4; ++r) {
                int row = bm0 + wm + i * 16 + quad * 4 + r;
                C[(size_t)row * 512 + col] = acc[i][j][r];
            }
        }
}

// ---------------------------------------------------------------------------
extern "C" void kernel_launch(void* const* d_in, const int* in_sizes, int n_in,
                              void* d_out, int out_size, void* d_ws, size_t ws_size,
                              hipStream_t stream) {
    const float* x = (const float*)d_in[0];
    const float* Wq = (const float*)d_in[1];
    const float* Wk = (const float*)d_in[2];
    const float* Wv = (const float*)d_in[3];
    const float* Wo = (const float*)d_in[4];
    const float* Wiq = (const float*)d_in[5];
    const float* Wik = (const float*)d_in[6];
    const float* Wiw = (const float*)d_in[7];
    const float* biw = (const float*)d_in[8];
    const float* idx_bias = (const float*)d_in[9];
    const float* Wvg = (const float*)d_in[10];
    const float* bvg = (const float*)d_in[11];
    const float* Wog = (const float*)d_in[12];
    const float* bog = (const float*)d_in[13];
    float* out = (float*)d_out;
    char* base = (char*)d_ws;

    float* qb = (float*)(base + 0);                  //  0-4M fp32 q
    float* kb = (float*)(base + (4ull << 20));       //  4-8M fp32 k (pre-rope)
    float* vb = (float*)(base + (8ull << 20));       //  8-12M fp32 v (dead after late)
    ushort* ab_bf = (ushort*)(base + (8ull << 20));  // overlays dead vb
    float* vgb = (float*)(base + (12ull << 20));     // 12-16M vg (live thru late)
    float* ogb = (float*)(base + (16ull << 20));     // 16-20M og gate
    float* qib = (float*)(base + (20ull << 20));     // 20-22M (memset 0)
    float* kib = (float*)(base + (22ull << 20));     // 22-22.5M (memset 0)
    float* wsb = (float*)(base + (22ull << 20) + (512u << 10));  // 32KB
    ushort* xb = (ushort*)(base + (23ull << 20));    // 23-25M bf16 x (dead after mid)
    int* idxb = (int*)(base + (23ull << 20));        // overlays dead xb, 1MB
    int* cntb = (int*)(base + (24ull << 20));        // overlays dead xb, 8KB
    ushort* wtb = (ushort*)(base + (25ull << 20));   // 25-28M bf16 W^T x6
    ushort* kb16 = (ushort*)(base + (28ull << 20));  // 28-30M bf16 K post-rope
    ushort* vb16 = (ushort*)(base + (30ull << 20));  // 30-32M bf16 V gated
    unsigned* keysb = (unsigned*)(base + (32ull << 20));  // 32-48M keys

    dim3 blk(256);
    hipMemsetAsync(qib, 0, (size_t)(TT * NI * DI + TT * DI) * sizeof(float), stream);
    prep_kernel<<<3392, blk, 0, stream>>>(x, Wq, Wk, Wv, Wvg, Wog, Wo, Wiq, Wik,
                                          Wiw, biw, xb, wtb, qib, kib, wsb);
    mid_kernel<<<1808, blk, 0, stream>>>(xb, wtb, qb, kb, vb, vgb, ogb, bvg, bog,
                                         qib, kib, wsb, idx_bias, keysb);
    late_kernel<<<5120, blk, 0, stream>>>(keysb, idxb, cntb, vb, vgb, vb16, qb,
                                          kb, kb16);
    attn_kernel<<<dim3(TT, 2), blk, 0, stream>>>(qb, kb16, vb16, ogb, idxb, cntb, ab_bf);
    wo64_kernel<<<dim3(8, 32), blk, 0, stream>>>(ab_bf, wtb + (size_t)5 * 512 * 512, out);
}

// Round 17
// 230.768 us; speedup vs baseline: 1.0198x; 1.0198x over previous
//
#include <hip/hip_runtime.h>
#include <math.h>

#define TT 2048
#define DD 512
#define HEADS 8
#define DH 64
#define NI 4
#define DI 64
#define KSEL 128

typedef __bf16 bfr;
typedef bfr bf16x8 __attribute__((ext_vector_type(8)));
typedef float f32x4 __attribute__((ext_vector_type(4)));

__device__ __forceinline__ float sigmoidf_(float z) {
    return 1.0f / (1.0f + __expf(-z));
}

__device__ __forceinline__ ushort f2bf(float f) {
    unsigned u = __float_as_uint(f);
    unsigned r = (u + 0x7fffu + ((u >> 16) & 1u)) >> 16;
    return (ushort)r;
}

__device__ __forceinline__ float bf2f(ushort u) {
    return __uint_as_float(((unsigned)u) << 16);
}

// ---------------------------------------------------------------------------
// fp32 64x64 GEMM tile, split-K with register prefetch; atomicAdd combine.
// ---------------------------------------------------------------------------
__device__ __forceinline__ void gemm_tile64_sk(const float* __restrict__ A,
                                               const float* __restrict__ B,
                                               float* __restrict__ C,
                                               int N, int bm, int bn0,
                                               int k0beg, int k0end) {
    __shared__ float Ast[16][64];
    __shared__ float Bs[16][64];
    int tid = threadIdx.x;
    int tx = tid & 15, ty = tid >> 4;
    int ma = tid >> 2, kq = tid & 3;
    int kb_ = tid >> 4, n4 = tid & 15;
    float acc[4][4] = {};
    float4 a_cur = *(const float4*)(A + (size_t)(bm + ma) * 512 + k0beg + kq * 4);
    float4 b_cur = *(const float4*)(B + (size_t)(k0beg + kb_) * N + bn0 + n4 * 4);
    for (int k0 = k0beg; k0 < k0end; k0 += 16) {
        *(float4*)&Bs[kb_][n4 * 4] = b_cur;
        Ast[kq * 4 + 0][ma] = a_cur.x;
        Ast[kq * 4 + 1][ma] = a_cur.y;
        Ast[kq * 4 + 2][ma] = a_cur.z;
        Ast[kq * 4 + 3][ma] = a_cur.w;
        __syncthreads();
        if (k0 + 16 < k0end) {
            a_cur = *(const float4*)(A + (size_t)(bm + ma) * 512 + k0 + 16 + kq * 4);
            b_cur = *(const float4*)(B + (size_t)(k0 + 16 + kb_) * N + bn0 + n4 * 4);
        }
#pragma unroll
        for (int kk = 0; kk < 16; ++kk) {
            float4 a4 = *(const float4*)&Ast[kk][ty * 4];
            float4 b4 = *(const float4*)&Bs[kk][tx * 4];
            float af[4] = {a4.x, a4.y, a4.z, a4.w};
            float bf[4] = {b4.x, b4.y, b4.z, b4.w};
#pragma unroll
            for (int i = 0; i < 4; ++i)
#pragma unroll
                for (int j = 0; j < 4; ++j) acc[i][j] += af[i] * bf[j];
        }
        __syncthreads();
    }
#pragma unroll
    for (int i = 0; i < 4; ++i) {
        int mrow = bm + ty * 4 + i;
#pragma unroll
        for (int j = 0; j < 4; ++j)
            atomicAdd(&C[(size_t)mrow * N + bn0 + tx * 4 + j], acc[i][j]);
    }
}

// ---------------------------------------------------------------------------
// prep: proj32-splitK (320) | castx (1024) | wtrans (1536) | iw (512) = 3392
// ---------------------------------------------------------------------------
__global__ __launch_bounds__(256) void prep_kernel(
    const float* __restrict__ x, const float* __restrict__ Wq,
    const float* __restrict__ Wk, const float* __restrict__ Wv,
    const float* __restrict__ Wvg, const float* __restrict__ Wog,
    const float* __restrict__ Wo, const float* __restrict__ Wiq,
    const float* __restrict__ Wik, const float* __restrict__ Wiw,
    const float* __restrict__ biw, ushort* __restrict__ xb,
    ushort* __restrict__ wtb, float* __restrict__ qib,
    float* __restrict__ kib, float* __restrict__ wsb) {
    int b = blockIdx.x, tid = threadIdx.x;
    if (b < 320) {
        int tp = b >> 1, kh = b & 1;
        int bn = tp % 5, bm = (tp / 5) * 64;
        int k0beg = kh * 256, k0end = k0beg + 256;
        if (bn < 4)
            gemm_tile64_sk(x, Wiq, qib, 256, bm, bn * 64, k0beg, k0end);
        else
            gemm_tile64_sk(x, Wik, kib, 64, bm, 0, k0beg, k0end);
    } else if (b < 1344) {
        int e = (b - 320) * 256 + tid;
        float4 v = ((const float4*)x)[e];
        ushort4 r;
        r.x = f2bf(v.x); r.y = f2bf(v.y); r.z = f2bf(v.z); r.w = f2bf(v.w);
        ((ushort4*)xb)[e] = r;
    } else if (b < 2880) {
        __shared__ float t[32][33];
        int p = b - 1344;
        int mat = p >> 8, tt = p & 255;
        int n0 = (tt & 15) * 32, k0 = (tt >> 4) * 32;
        const float* srcs[6] = {Wq, Wk, Wv, Wvg, Wog, Wo};
        const float* W = srcs[mat];
        ushort* outp = wtb + (size_t)mat * 512 * 512;
        int c = tid & 31, r8 = tid >> 5;
#pragma unroll
        for (int rr = 0; rr < 32; rr += 8)
            t[r8 + rr][c] = W[(size_t)(k0 + r8 + rr) * 512 + n0 + c];
        __syncthreads();
#pragma unroll
        for (int rr = 0; rr < 32; rr += 8)
            outp[(size_t)(n0 + r8 + rr) * 512 + k0 + c] = f2bf(t[c][r8 + rr]);
    } else {
        int lane = tid & 63, wv = tid >> 6;
        int row = (b - 2880) * 4 + wv;
        float a0 = 0.f, a1 = 0.f, a2 = 0.f, a3 = 0.f;
        for (int k = lane; k < DD; k += 64) {
            float xv = x[row * DD + k];
            float4 wv4 = *(const float4*)(Wiw + k * NI);
            a0 += xv * wv4.x; a1 += xv * wv4.y;
            a2 += xv * wv4.z; a3 += xv * wv4.w;
        }
#pragma unroll
        for (int off = 32; off; off >>= 1) {
            a0 += __shfl_down(a0, off);
            a1 += __shfl_down(a1, off);
            a2 += __shfl_down(a2, off);
            a3 += __shfl_down(a3, off);
        }
        if (lane == 0) {
            wsb[row * NI + 0] = sigmoidf_(a0 + biw[0]);
            wsb[row * NI + 1] = sigmoidf_(a1 + biw[1]);
            wsb[row * NI + 2] = sigmoidf_(a2 + biw[2]);
            wsb[row * NI + 3] = sigmoidf_(a3 + biw[3]);
        }
    }
}

// ---------------------------------------------------------------------------
// mid: MFMA projections 128x128 tiles (blocks 0..319) | score (320..847).
// Score stages BOTH operands k-major so fragments read as ds_read_b128.
// ---------------------------------------------------------------------------
__global__ __launch_bounds__(256) void mid_kernel(
    const ushort* __restrict__ A, const ushort* __restrict__ BT,
    float* __restrict__ qo, float* __restrict__ ko, float* __restrict__ vo,
    float* __restrict__ vgo, float* __restrict__ ogo,
    const float* __restrict__ bvg, const float* __restrict__ bog,
    const float* __restrict__ qi, const float* __restrict__ ki,
    const float* __restrict__ wsig, const float* __restrict__ idx_bias,
    unsigned* __restrict__ keys) {
    __shared__ union {
        struct {
            __align__(16) ushort As[128][32];
            __align__(16) ushort Bs[128][32];
        } mf;
        struct {
            float As[64][65];  // [k][m]
            float Bs[64][65];  // [k][n]
        } sc;
    } u;
    int gb = blockIdx.x;
    int tid = threadIdx.x;
    if (gb < 320) {
        // ------------------ MFMA bf16 projections, 128x128 tile ------------------
        const int K = 512;
        int bx = gb % 20, by = gb / 20;
        int bm0 = by * 128;
        int bn_cat = bx * 128;
        int w = tid >> 6, lane = tid & 63;
        int wm = (w >> 1) * 64, wn = (w & 1) * 64;
        int quad = lane >> 4, mr = lane & 15;
        f32x4 acc[4][4];
#pragma unroll
        for (int i = 0; i < 4; ++i)
#pragma unroll
            for (int j = 0; j < 4; ++j)
#pragma unroll
                for (int r = 0; r < 4; ++r) acc[i][j][r] = 0.f;
        int rs = tid >> 2, cs = (tid & 3) * 8;
        int rs2 = (tid + 256) >> 2;
        for (int k0 = 0; k0 < K; k0 += 32) {
            *(float4*)&u.mf.As[rs][cs] =
                *(const float4*)(A + (size_t)(bm0 + rs) * K + k0 + cs);
            *(float4*)&u.mf.Bs[rs][cs] =
                *(const float4*)(BT + (size_t)(bn_cat + rs) * K + k0 + cs);
            *(float4*)&u.mf.As[rs2][cs] =
                *(const float4*)(A + (size_t)(bm0 + rs2) * K + k0 + cs);
            *(float4*)&u.mf.Bs[rs2][cs] =
                *(const float4*)(BT + (size_t)(bn_cat + rs2) * K + k0 + cs);
            __syncthreads();
            bf16x8 af[4], bfv[4];
#pragma unroll
            for (int i = 0; i < 4; ++i)
                af[i] = *(const bf16x8*)&u.mf.As[wm + i * 16 + mr][quad * 8];
#pragma unroll
            for (int j = 0; j < 4; ++j)
                bfv[j] = *(const bf16x8*)&u.mf.Bs[wn + j * 16 + mr][quad * 8];
#pragma unroll
            for (int i = 0; i < 4; ++i)
#pragma unroll
                for (int j = 0; j < 4; ++j)
                    acc[i][j] = __builtin_amdgcn_mfma_f32_16x16x32_bf16(
                        af[i], bfv[j], acc[i][j], 0, 0, 0);
            __syncthreads();
        }
        int mat = bx >> 2;
        float* C = mat == 0 ? qo : mat == 1 ? ko : mat == 2 ? vo : mat == 3 ? vgo : ogo;
        const float* bias = mat == 3 ? bvg : mat == 4 ? bog : nullptr;
        int bn0 = (bx & 3) * 128;
#pragma unroll
        for (int i = 0; i < 4; ++i)
#pragma unroll
            for (int j = 0; j < 4; ++j) {
                int col = bn0 + wn + j * 16 + mr;
                float bv = bias ? bias[col] : 0.f;
#pragma unroll
                for (int r = 0; r < 4; ++r) {
                    int row = bm0 + wm + i * 16 + quad * 4 + r;
                    float val = acc[i][j][r];
                    if (bias) val = sigmoidf_(val + bv);
                    C[(size_t)row * 512 + col] = val;
                }
            }
    } else {
        // ------------------ index-score lower-triangle tiles ------------------
        int b = gb - 320;
        int bq = (int)((sqrtf(8.0f * (float)b + 1.0f) - 1.0f) * 0.5f);
        while ((bq + 1) * (bq + 2) / 2 <= b) ++bq;
        while (bq * (bq + 1) / 2 > b) --bq;
        int bk = b - bq * (bq + 1) / 2;
        int q0 = bq * 64, k0 = bk * 64;
        int tx = tid & 15, ty = tid >> 4;
        float fin[4][4] = {};
        // stage Bs once ([k][n], k-major) and As head 0 ([k][m], k-major)
#pragma unroll
        for (int i = 0; i < 4; ++i) {
            int e = tid + i * 256;
            int r = e >> 4, c4 = e & 15;
            float4 bv = *(const float4*)(ki + (size_t)(k0 + r) * DI + c4 * 4);
            u.sc.Bs[c4 * 4 + 0][r] = bv.x;
            u.sc.Bs[c4 * 4 + 1][r] = bv.y;
            u.sc.Bs[c4 * 4 + 2][r] = bv.z;
            u.sc.Bs[c4 * 4 + 3][r] = bv.w;
            float4 av = *(const float4*)(qi + (size_t)(q0 + r) * (NI * DI) + c4 * 4);
            u.sc.As[c4 * 4 + 0][r] = av.x;
            u.sc.As[c4 * 4 + 1][r] = av.y;
            u.sc.As[c4 * 4 + 2][r] = av.z;
            u.sc.As[c4 * 4 + 3][r] = av.w;
        }
        __syncthreads();
#pragma unroll
        for (int h = 0; h < NI; ++h) {
            float raw[4][4] = {};
#pragma unroll 8
            for (int kk = 0; kk < 64; ++kk) {
                float4 a4 = *(const float4*)&u.sc.As[kk][ty * 4];
                float4 b4 = *(const float4*)&u.sc.Bs[kk][tx * 4];
                float a[4] = {a4.x, a4.y, a4.z, a4.w};
                float bb[4] = {b4.x, b4.y, b4.z, b4.w};
#pragma unroll
                for (int i = 0; i < 4; ++i)
#pragma unroll
                    for (int j = 0; j < 4; ++j) raw[i][j] += a[i] * bb[j];
            }
            float bh = idx_bias[h];
            float w4[4];
#pragma unroll
            for (int i = 0; i < 4; ++i) w4[i] = wsig[(q0 + ty * 4 + i) * NI + h];
#pragma unroll
            for (int i = 0; i < 4; ++i)
#pragma unroll
                for (int j = 0; j < 4; ++j)
                    fin[i][j] += sigmoidf_(raw[i][j] * 0.125f + bh) * w4[i];
            if (h < NI - 1) {
                __syncthreads();
#pragma unroll
                for (int i = 0; i < 4; ++i) {
                    int e = tid + i * 256;
                    int r = e >> 4, c4 = e & 15;
                    float4 av = *(const float4*)(qi + (size_t)(q0 + r) * (NI * DI) +
                                                 (h + 1) * DI + c4 * 4);
                    u.sc.As[c4 * 4 + 0][r] = av.x;
                    u.sc.As[c4 * 4 + 1][r] = av.y;
                    u.sc.As[c4 * 4 + 2][r] = av.z;
                    u.sc.As[c4 * 4 + 3][r] = av.w;
                }
                __syncthreads();
            }
        }
#pragma unroll
        for (int i = 0; i < 4; ++i) {
            int qq = q0 + ty * 4 + i;
#pragma unroll
            for (int j = 0; j < 4; ++j) {
                int kk = k0 + tx * 4 + j;
                unsigned key = 0;
                if (kk <= qq) {
                    unsigned uu = __float_as_uint(fin[i][j]);
                    key = (uu & 0x80000000u) ? ~uu : (uu | 0x80000000u);
                }
                keys[(size_t)qq * TT + kk] = key;
            }
        }
    }
}

// ---------------------------------------------------------------------------
// late: topk (blocks 0..2047) | post vmul+rope (2048..5119).
// ---------------------------------------------------------------------------
__global__ __launch_bounds__(256) void late_kernel(
    const unsigned* __restrict__ keys, int* __restrict__ indices,
    int* __restrict__ counts, const float* __restrict__ vb,
    const float* __restrict__ vgb, ushort* __restrict__ v16,
    float* __restrict__ q, const float* __restrict__ k,
    ushort* __restrict__ k16) {
    __shared__ unsigned ks_[TT];
    __shared__ unsigned hist[256];
    __shared__ unsigned wtot[4];
    __shared__ unsigned s_prefix, s_above;
    __shared__ int eqlist[256];
    __shared__ unsigned eqcount, outpos;
    int gb = blockIdx.x;
    int tid = threadIdx.x;
    if (gb >= 2048) {
        int b = gb - 2048;
        if (b < 1024) {
            int e = b * 256 + tid;
            float4 v = ((const float4*)vb)[e];
            float4 g = ((const float4*)vgb)[e];
            ushort4 r;
            r.x = f2bf(v.x * g.x); r.y = f2bf(v.y * g.y);
            r.z = f2bf(v.z * g.z); r.w = f2bf(v.w * g.w);
            ((ushort4*)v16)[e] = r;
        } else {
            int i = (b - 1024) * 256 + tid;
            int j = i & 31;
            int h = (i >> 5) & 7;
            int t = i >> 8;
            const float L2_10000 = 13.287712379549449f;
            float inv = exp2f(-(float)j * (1.0f / 32.0f) * L2_10000);
            float ang = (float)t * inv;
            float c = cosf(ang), s = sinf(ang);
            int base = t * DD + h * DH;
            float q1 = q[base + j], q2 = q[base + j + 32];
            q[base + j] = q1 * c - q2 * s;
            q[base + j + 32] = q2 * c + q1 * s;
            float k1 = k[base + j], k2 = k[base + j + 32];
            k16[base + j] = f2bf(k1 * c - k2 * s);
            k16[base + j + 32] = f2bf(k2 * c + k1 * s);
        }
        return;
    }
    int qrow = gb;
    int lane = tid & 63, wv = tid >> 6;
    int n = qrow + 1;
    if (n <= KSEL) {
        if (tid < n) indices[qrow * KSEL + tid] = tid;
        if (tid == 0) counts[qrow] = n;
        return;
    }
    if (tid == 0) counts[qrow] = KSEL;
    const unsigned* krow = keys + (size_t)qrow * TT;
    for (int k_ = tid; k_ < n; k_ += 256) ks_[k_] = krow[k_];
    __syncthreads();
    unsigned prefix = 0;
    int remaining = KSEL;
    for (int level = 24; level >= 0; level -= 8) {
        hist[tid] = 0;
        __syncthreads();
        for (int k_ = tid; k_ < n; k_ += 256) {
            unsigned key = ks_[k_];
            bool match = ((unsigned long long)key >> (level + 8)) == (unsigned long long)prefix;
            if (match) atomicAdd(&hist[(key >> level) & 255], 1u);
        }
        __syncthreads();
        unsigned v = hist[tid];
#pragma unroll
        for (int off = 1; off < 64; off <<= 1) {
            unsigned t = __shfl_down(v, off);
            if (lane + off < 64) v += t;
        }
        if (lane == 0) wtot[wv] = v;
        __syncthreads();
        unsigned add = 0;
#pragma unroll
        for (int uu = 1; uu < 4; ++uu)
            if (wv + uu < 4) add += wtot[wv + uu];
        v += add;
        hist[tid] = v;
        __syncthreads();
        if (hist[tid] >= (unsigned)remaining &&
            (tid == 255 || hist[tid + 1] < (unsigned)remaining)) {
            s_prefix = (prefix << 8) | (unsigned)tid;
            s_above = (tid == 255) ? 0u : hist[tid + 1];
        }
        __syncthreads();
        prefix = s_prefix;
        remaining -= (int)s_above;
        __syncthreads();
    }
    if (tid == 0) { eqcount = 0; outpos = 0; }
    __syncthreads();
    int outbase = qrow * KSEL;
    for (int k_ = tid; k_ < n; k_ += 256) {
        unsigned key = ks_[k_];
        if (key > prefix) {
            unsigned p = atomicAdd(&outpos, 1u);
            indices[outbase + p] = k_;
        } else if (key == prefix) {
            unsigned e = atomicAdd(&eqcount, 1u);
            if (e < 256) eqlist[e] = k_;
        }
    }
    __syncthreads();
    if (tid == 0) {
        int r = remaining;
        int E = (int)eqcount;
        if (E > 256) E = 256;
        if (r > E) r = E;
        int pos = (int)outpos;
        for (int t = 0; t < r; ++t) {
            int best = 0x7fffffff, bj = -1;
            for (int j = 0; j < E; ++j) {
                int vv = eqlist[j];
                if (vv < best) { best = vv; bj = j; }
            }
            eqlist[bj] = 0x7fffffff;
            indices[outbase + pos + t] = best;
        }
    }
}

// ---------------------------------------------------------------------------
// Sparse attention: grid (TT,2), wave w owns head blockIdx.y*4+w.
// ---------------------------------------------------------------------------
__global__ __launch_bounds__(256) void attn_kernel(
    const float* __restrict__ q, const ushort* __restrict__ k16,
    const ushort* __restrict__ v16, const float* __restrict__ og,
    const int* __restrict__ indices, const int* __restrict__ counts,
    ushort* __restrict__ out) {
    __shared__ int idx[KSEL];
    __shared__ ushort kw[4][32 * 68];
    __shared__ float qv[4][DH];
    __shared__ float pw[4][KSEL];
    int qrow = blockIdx.x;
    int tid = threadIdx.x;
    int lane = tid & 63, w = tid >> 6;
    int cnt = counts[qrow];
    if (tid < KSEL) idx[tid] = (tid < cnt) ? indices[qrow * KSEL + tid] : 0;
    __syncthreads();
    ushort* kws = kw[w];
    float* qvs = qv[w];
    float* pps = pw[w];
    int h = blockIdx.y * 4 + w;
    int hb = h * DH;
    qvs[lane] = q[qrow * DD + hb + lane];
    int j2 = lane & 31, half = lane >> 5;
    int r4 = lane >> 4, cs = (lane & 15) * 4;
    float sc[4];
#pragma unroll
    for (int c = 0; c < 4; ++c) {
#pragma unroll
        for (int it = 0; it < 8; ++it) {
            int r = it * 4 + r4;
            int row = idx[c * 32 + r];
            *(ushort4*)&kws[r * 68 + cs] =
                *(const ushort4*)(k16 + (size_t)row * DD + hb + cs);
        }
        float acc0 = 0.f, acc1 = 0.f;
        const ushort* kr = kws + j2 * 68 + half * 32;
        const float* qr = qvs + half * 32;
#pragma unroll
        for (int dd = 0; dd < 8; dd += 2) {
            ushort4 ka = *(const ushort4*)&kr[dd * 4];
            ushort4 kb_ = *(const ushort4*)&kr[dd * 4 + 4];
            acc0 += bf2f(ka.x) * qr[dd * 4 + 0] + bf2f(ka.y) * qr[dd * 4 + 1] +
                    bf2f(ka.z) * qr[dd * 4 + 2] + bf2f(ka.w) * qr[dd * 4 + 3];
            acc1 += bf2f(kb_.x) * qr[dd * 4 + 4] + bf2f(kb_.y) * qr[dd * 4 + 5] +
                    bf2f(kb_.z) * qr[dd * 4 + 6] + bf2f(kb_.w) * qr[dd * 4 + 7];
        }
        float acc = acc0 + acc1;
        acc += __shfl_xor(acc, 32);
        int j = c * 32 + j2;
        sc[c] = (j < cnt) ? acc * 0.125f : -1e30f;
    }
    float m = fmaxf(fmaxf(sc[0], sc[1]), fmaxf(sc[2], sc[3]));
#pragma unroll
    for (int off = 16; off; off >>= 1) m = fmaxf(m, __shfl_xor(m, off));
    float pc[4], sum = 0.f;
#pragma unroll
    for (int c = 0; c < 4; ++c) {
        pc[c] = __expf(sc[c] - m);
        sum += pc[c];
    }
#pragma unroll
    for (int off = 16; off; off >>= 1) sum += __shfl_xor(sum, off);
    float inv = 1.0f / sum;
    if (half == 0) {
#pragma unroll
        for (int c = 0; c < 4; ++c) pps[c * 32 + j2] = pc[c] * inv;
    }
    int dgroup = lane & 15, g = lane >> 4;
    int db = dgroup * 4;
    float a0 = 0.f, a1 = 0.f, a2 = 0.f, a3 = 0.f;
    float b0 = 0.f, b1 = 0.f, b2 = 0.f, b3 = 0.f;
#pragma unroll 8
    for (int t = 0; t < 32; t += 2) {
        int jA = g + 4 * t;
        int jB = g + 4 * t + 4;
        int rowA = idx[jA];
        int rowB = idx[jB];
        float pA = pps[jA], pB = pps[jB];
        ushort4 va = *(const ushort4*)(v16 + (size_t)rowA * DD + hb + db);
        ushort4 vb = *(const ushort4*)(v16 + (size_t)rowB * DD + hb + db);
        a0 += pA * bf2f(va.x); a1 += pA * bf2f(va.y);
        a2 += pA * bf2f(va.z); a3 += pA * bf2f(va.w);
        b0 += pB * bf2f(vb.x); b1 += pB * bf2f(vb.y);
        b2 += pB * bf2f(vb.z); b3 += pB * bf2f(vb.w);
    }
    a0 += b0; a1 += b1; a2 += b2; a3 += b3;
    a0 += __shfl_xor(a0, 16); a0 += __shfl_xor(a0, 32);
    a1 += __shfl_xor(a1, 16); a1 += __shfl_xor(a1, 32);
    a2 += __shfl_xor(a2, 16); a2 += __shfl_xor(a2, 32);
    a3 += __shfl_xor(a3, 16); a3 += __shfl_xor(a3, 32);
    if (g == 0) {
        int o = qrow * DD + hb + db;
        float4 gg = *(const float4*)(og + o);
        ushort4 r;
        r.x = f2bf(a0 * gg.x);
        r.y = f2bf(a1 * gg.y);
        r.z = f2bf(a2 * gg.z);
        r.w = f2bf(a3 * gg.w);
        *(ushort4*)(out + o) = r;
    }
}

// ---------------------------------------------------------------------------
// Wo MFMA GEMM, 64x64 tile (4 waves x 2x2 fragments) -> 256 blocks.
// ---------------------------------------------------------------------------
__global__ __launch_bounds__(256) void wo64_kernel(
    const ushort* __restrict__ A, const ushort* __restrict__ BT,
    float* __restrict__ C) {
    __shared__ __align__(16) ushort As[64][32];
    __shared__ __align__(16) ushort Bs[64][32];
    const int K = 512;
    int tid = threadIdx.x;
    int bm0 = blockIdx.y * 64, bn0 = blockIdx.x * 64;
    int w = tid >> 6, lane = tid & 63;
    int wm = (w >> 1) * 32, wn = (w & 1) * 32;
    int quad = lane >> 4, mr = lane & 15;
    f32x4 acc[2][2];
#pragma unroll
    for (int i = 0; i < 2; ++i)
#pragma unroll
        for (int j = 0; j < 2; ++j)
#pragma unroll
            for (int r = 0; r < 4; ++r) acc[i][j][r] = 0.f;
    int rs = tid >> 2, cs = (tid & 3) * 8;
    for (int k0 = 0; k0 < K; k0 += 32) {
        *(float4*)&As[rs][cs] = *(const float4*)(A + (size_t)(bm0 + rs) * K + k0 + cs);
        *(float4*)&Bs[rs][cs] = *(const float4*)(BT + (size_t)(bn0 + rs) * K + k0 + cs);
        __syncthreads();
        bf16x8 af[2], bfv[2];
#pragma unroll
        for (int i = 0; i < 2; ++i)
            af[i] = *(const bf16x8*)&As[wm + i * 16 + mr][quad * 8];
#pragma unroll
        for (int j = 0; j < 2; ++j)
            bfv[j] = *(const bf16x8*)&Bs[wn + j * 16 + mr][quad * 8];
#pragma unroll
        for (int i = 0; i < 2; ++i)
#pragma unroll
            for (int j = 0; j < 2; ++j)
                acc[i][j] = __builtin_amdgcn_mfma_f32_16x16x32_bf16(
                    af[i], bfv[j], acc[i][j], 0, 0, 0);
        __syncthreads();
    }
#pragma unroll
    for (int i = 0; i < 2; ++i)
#pragma unroll
        for (int j = 0; j < 2; ++j) {
            int col = bn0 + wn + j * 16 + mr;
#pragma unroll
            for (int r = 0; r < 4; ++r) {
                int row = bm0 + wm + i * 16 + quad * 4 + r;
                C[(size_t)row * 512 + col] = acc[i][j][r];
            }
        }
}

// ---------------------------------------------------------------------------
extern "C" void kernel_launch(void* const* d_in, const int* in_sizes, int n_in,
                              void* d_out, int out_size, void* d_ws, size_t ws_size,
                              hipStream_t stream) {
    const float* x = (const float*)d_in[0];
    const float* Wq = (const float*)d_in[1];
    const float* Wk = (const float*)d_in[2];
    const float* Wv = (const float*)d_in[3];
    const float* Wo = (const float*)d_in[4];
    const float* Wiq = (const float*)d_in[5];
    const float* Wik = (const float*)d_in[6];
    const float* Wiw = (const float*)d_in[7];
    const float* biw = (const float*)d_in[8];
    const float* idx_bias = (const float*)d_in[9];
    const float* Wvg = (const float*)d_in[10];
    const float* bvg = (const float*)d_in[11];
    const float* Wog = (const float*)d_in[12];
    const float* bog = (const float*)d_in[13];
    float* out = (float*)d_out;
    char* base = (char*)d_ws;

    float* qb = (float*)(base + 0);                  //  0-4M fp32 q
    float* kb = (float*)(base + (4ull << 20));       //  4-8M fp32 k (pre-rope)
    float* vb = (float*)(base + (8ull << 20));       //  8-12M fp32 v (dead after late)
    ushort* ab_bf = (ushort*)(base + (8ull << 20));  // overlays dead vb
    float* vgb = (float*)(base + (12ull << 20));     // 12-16M vg (live thru late)
    float* ogb = (float*)(base + (16ull << 20));     // 16-20M og gate
    float* qib = (float*)(base + (20ull << 20));     // 20-22M (memset 0)
    float* kib = (float*)(base + (22ull << 20));     // 22-22.5M (memset 0)
    float* wsb = (float*)(base + (22ull << 20) + (512u << 10));  // 32KB
    ushort* xb = (ushort*)(base + (23ull << 20));    // 23-25M bf16 x (dead after mid)
    int* idxb = (int*)(base + (23ull << 20));        // overlays dead xb, 1MB
    int* cntb = (int*)(base + (24ull << 20));        // overlays dead xb, 8KB
    ushort* wtb = (ushort*)(base + (25ull << 20));   // 25-28M bf16 W^T x6
    ushort* kb16 = (ushort*)(base + (28ull << 20));  // 28-30M bf16 K post-rope
    ushort* vb16 = (ushort*)(base + (30ull << 20));  // 30-32M bf16 V gated
    unsigned* keysb = (unsigned*)(base + (32ull << 20));  // 32-48M keys

    dim3 blk(256);
    hipMemsetAsync(qib, 0, (size_t)(TT * NI * DI + TT * DI) * sizeof(float), stream);
    prep_kernel<<<3392, blk, 0, stream>>>(x, Wq, Wk, Wv, Wvg, Wog, Wo, Wiq, Wik,
                                          Wiw, biw, xb, wtb, qib, kib, wsb);
    mid_kernel<<<848, blk, 0, stream>>>(xb, wtb, qb, kb, vb, vgb, ogb, bvg, bog,
                                        qib, kib, wsb, idx_bias, keysb);
    late_kernel<<<5120, blk, 0, stream>>>(keysb, idxb, cntb, vb, vgb, vb16, qb,
                                          kb, kb16);
    attn_kernel<<<dim3(TT, 2), blk, 0, stream>>>(qb, kb16, vb16, ogb, idxb, cntb, ab_bf);
    wo64_kernel<<<dim3(8, 32), blk, 0, stream>>>(ab_bf, wtb + (size_t)5 * 512 * 512, out);
}

// Round 18
// 229.306 us; speedup vs baseline: 1.0263x; 1.0064x over previous
//
#include <hip/hip_runtime.h>
#include <math.h>

#define TT 2048
#define DD 512
#define HEADS 8
#define DH 64
#define NI 4
#define DI 64
#define KSEL 128

typedef __bf16 bfr;
typedef bfr bf16x8 __attribute__((ext_vector_type(8)));
typedef float f32x4 __attribute__((ext_vector_type(4)));

__device__ __forceinline__ float sigmoidf_(float z) {
    return 1.0f / (1.0f + __expf(-z));
}

__device__ __forceinline__ ushort f2bf(float f) {
    unsigned u = __float_as_uint(f);
    unsigned r = (u + 0x7fffu + ((u >> 16) & 1u)) >> 16;
    return (ushort)r;
}

__device__ __forceinline__ float bf2f(ushort u) {
    return __uint_as_float(((unsigned)u) << 16);
}

// ---------------------------------------------------------------------------
// fp32 64x64 GEMM tile, split-K with register prefetch; atomicAdd combine.
// ---------------------------------------------------------------------------
__device__ __forceinline__ void gemm_tile64_sk(const float* __restrict__ A,
                                               const float* __restrict__ B,
                                               float* __restrict__ C,
                                               int N, int bm, int bn0,
                                               int k0beg, int k0end) {
    __shared__ float Ast[16][64];
    __shared__ float Bs[16][64];
    int tid = threadIdx.x;
    int tx = tid & 15, ty = tid >> 4;
    int ma = tid >> 2, kq = tid & 3;
    int kb_ = tid >> 4, n4 = tid & 15;
    float acc[4][4] = {};
    float4 a_cur = *(const float4*)(A + (size_t)(bm + ma) * 512 + k0beg + kq * 4);
    float4 b_cur = *(const float4*)(B + (size_t)(k0beg + kb_) * N + bn0 + n4 * 4);
    for (int k0 = k0beg; k0 < k0end; k0 += 16) {
        *(float4*)&Bs[kb_][n4 * 4] = b_cur;
        Ast[kq * 4 + 0][ma] = a_cur.x;
        Ast[kq * 4 + 1][ma] = a_cur.y;
        Ast[kq * 4 + 2][ma] = a_cur.z;
        Ast[kq * 4 + 3][ma] = a_cur.w;
        __syncthreads();
        if (k0 + 16 < k0end) {
            a_cur = *(const float4*)(A + (size_t)(bm + ma) * 512 + k0 + 16 + kq * 4);
            b_cur = *(const float4*)(B + (size_t)(k0 + 16 + kb_) * N + bn0 + n4 * 4);
        }
#pragma unroll
        for (int kk = 0; kk < 16; ++kk) {
            float4 a4 = *(const float4*)&Ast[kk][ty * 4];
            float4 b4 = *(const float4*)&Bs[kk][tx * 4];
            float af[4] = {a4.x, a4.y, a4.z, a4.w};
            float bf[4] = {b4.x, b4.y, b4.z, b4.w};
#pragma unroll
            for (int i = 0; i < 4; ++i)
#pragma unroll
                for (int j = 0; j < 4; ++j) acc[i][j] += af[i] * bf[j];
        }
        __syncthreads();
    }
#pragma unroll
    for (int i = 0; i < 4; ++i) {
        int mrow = bm + ty * 4 + i;
#pragma unroll
        for (int j = 0; j < 4; ++j)
            atomicAdd(&C[(size_t)mrow * N + bn0 + tx * 4 + j], acc[i][j]);
    }
}

// ---------------------------------------------------------------------------
// prep: proj32-splitK (320) | castx (1024) | wtrans (1536) | iw (512) = 3392
// ---------------------------------------------------------------------------
__global__ __launch_bounds__(256) void prep_kernel(
    const float* __restrict__ x, const float* __restrict__ Wq,
    const float* __restrict__ Wk, const float* __restrict__ Wv,
    const float* __restrict__ Wvg, const float* __restrict__ Wog,
    const float* __restrict__ Wo, const float* __restrict__ Wiq,
    const float* __restrict__ Wik, const float* __restrict__ Wiw,
    const float* __restrict__ biw, ushort* __restrict__ xb,
    ushort* __restrict__ wtb, float* __restrict__ qib,
    float* __restrict__ kib, float* __restrict__ wsb) {
    int b = blockIdx.x, tid = threadIdx.x;
    if (b < 320) {
        int tp = b >> 1, kh = b & 1;
        int bn = tp % 5, bm = (tp / 5) * 64;
        int k0beg = kh * 256, k0end = k0beg + 256;
        if (bn < 4)
            gemm_tile64_sk(x, Wiq, qib, 256, bm, bn * 64, k0beg, k0end);
        else
            gemm_tile64_sk(x, Wik, kib, 64, bm, 0, k0beg, k0end);
    } else if (b < 1344) {
        int e = (b - 320) * 256 + tid;
        float4 v = ((const float4*)x)[e];
        ushort4 r;
        r.x = f2bf(v.x); r.y = f2bf(v.y); r.z = f2bf(v.z); r.w = f2bf(v.w);
        ((ushort4*)xb)[e] = r;
    } else if (b < 2880) {
        __shared__ float t[32][33];
        int p = b - 1344;
        int mat = p >> 8, tt = p & 255;
        int n0 = (tt & 15) * 32, k0 = (tt >> 4) * 32;
        const float* srcs[6] = {Wq, Wk, Wv, Wvg, Wog, Wo};
        const float* W = srcs[mat];
        ushort* outp = wtb + (size_t)mat * 512 * 512;
        int c = tid & 31, r8 = tid >> 5;
#pragma unroll
        for (int rr = 0; rr < 32; rr += 8)
            t[r8 + rr][c] = W[(size_t)(k0 + r8 + rr) * 512 + n0 + c];
        __syncthreads();
#pragma unroll
        for (int rr = 0; rr < 32; rr += 8)
            outp[(size_t)(n0 + r8 + rr) * 512 + k0 + c] = f2bf(t[c][r8 + rr]);
    } else {
        int lane = tid & 63, wv = tid >> 6;
        int row = (b - 2880) * 4 + wv;
        float a0 = 0.f, a1 = 0.f, a2 = 0.f, a3 = 0.f;
        for (int k = lane; k < DD; k += 64) {
            float xv = x[row * DD + k];
            float4 wv4 = *(const float4*)(Wiw + k * NI);
            a0 += xv * wv4.x; a1 += xv * wv4.y;
            a2 += xv * wv4.z; a3 += xv * wv4.w;
        }
#pragma unroll
        for (int off = 32; off; off >>= 1) {
            a0 += __shfl_down(a0, off);
            a1 += __shfl_down(a1, off);
            a2 += __shfl_down(a2, off);
            a3 += __shfl_down(a3, off);
        }
        if (lane == 0) {
            wsb[row * NI + 0] = sigmoidf_(a0 + biw[0]);
            wsb[row * NI + 1] = sigmoidf_(a1 + biw[1]);
            wsb[row * NI + 2] = sigmoidf_(a2 + biw[2]);
            wsb[row * NI + 3] = sigmoidf_(a3 + biw[3]);
        }
    }
}

// ---------------------------------------------------------------------------
// mid: MFMA projections 128x128 tiles (blocks 0..319) | score (320..847).
// Both branches use register prefetch to hide global-load latency.
// ---------------------------------------------------------------------------
__global__ __launch_bounds__(256) void mid_kernel(
    const ushort* __restrict__ A, const ushort* __restrict__ BT,
    float* __restrict__ qo, float* __restrict__ ko, float* __restrict__ vo,
    float* __restrict__ vgo, float* __restrict__ ogo,
    const float* __restrict__ bvg, const float* __restrict__ bog,
    const float* __restrict__ qi, const float* __restrict__ ki,
    const float* __restrict__ wsig, const float* __restrict__ idx_bias,
    unsigned* __restrict__ keys) {
    __shared__ union {
        struct {
            __align__(16) ushort As[128][32];
            __align__(16) ushort Bs[128][32];
        } mf;
        struct {
            float As[64][65];  // [k][m]
            float Bs[64][65];  // [k][n]
        } sc;
    } u;
    int gb = blockIdx.x;
    int tid = threadIdx.x;
    if (gb < 320) {
        // ---- MFMA bf16 projections, 128x128 tile, register-prefetched staging
        const int K = 512;
        int bx = gb % 20, by = gb / 20;
        int bm0 = by * 128;
        int bn_cat = bx * 128;
        int w = tid >> 6, lane = tid & 63;
        int wm = (w >> 1) * 64, wn = (w & 1) * 64;
        int quad = lane >> 4, mr = lane & 15;
        f32x4 acc[4][4];
#pragma unroll
        for (int i = 0; i < 4; ++i)
#pragma unroll
            for (int j = 0; j < 4; ++j)
#pragma unroll
                for (int r = 0; r < 4; ++r) acc[i][j][r] = 0.f;
        int rs = tid >> 2, cs = (tid & 3) * 8;
        int rs2 = (tid + 256) >> 2;
        float4 pa = *(const float4*)(A + (size_t)(bm0 + rs) * K + cs);
        float4 pb = *(const float4*)(BT + (size_t)(bn_cat + rs) * K + cs);
        float4 pa2 = *(const float4*)(A + (size_t)(bm0 + rs2) * K + cs);
        float4 pb2 = *(const float4*)(BT + (size_t)(bn_cat + rs2) * K + cs);
        for (int k0 = 0; k0 < K; k0 += 32) {
            *(float4*)&u.mf.As[rs][cs] = pa;
            *(float4*)&u.mf.Bs[rs][cs] = pb;
            *(float4*)&u.mf.As[rs2][cs] = pa2;
            *(float4*)&u.mf.Bs[rs2][cs] = pb2;
            __syncthreads();
            if (k0 + 32 < K) {
                pa = *(const float4*)(A + (size_t)(bm0 + rs) * K + k0 + 32 + cs);
                pb = *(const float4*)(BT + (size_t)(bn_cat + rs) * K + k0 + 32 + cs);
                pa2 = *(const float4*)(A + (size_t)(bm0 + rs2) * K + k0 + 32 + cs);
                pb2 = *(const float4*)(BT + (size_t)(bn_cat + rs2) * K + k0 + 32 + cs);
            }
            bf16x8 af[4], bfv[4];
#pragma unroll
            for (int i = 0; i < 4; ++i)
                af[i] = *(const bf16x8*)&u.mf.As[wm + i * 16 + mr][quad * 8];
#pragma unroll
            for (int j = 0; j < 4; ++j)
                bfv[j] = *(const bf16x8*)&u.mf.Bs[wn + j * 16 + mr][quad * 8];
#pragma unroll
            for (int i = 0; i < 4; ++i)
#pragma unroll
                for (int j = 0; j < 4; ++j)
                    acc[i][j] = __builtin_amdgcn_mfma_f32_16x16x32_bf16(
                        af[i], bfv[j], acc[i][j], 0, 0, 0);
            __syncthreads();
        }
        int mat = bx >> 2;
        float* C = mat == 0 ? qo : mat == 1 ? ko : mat == 2 ? vo : mat == 3 ? vgo : ogo;
        const float* bias = mat == 3 ? bvg : mat == 4 ? bog : nullptr;
        int bn0 = (bx & 3) * 128;
#pragma unroll
        for (int i = 0; i < 4; ++i)
#pragma unroll
            for (int j = 0; j < 4; ++j) {
                int col = bn0 + wn + j * 16 + mr;
                float bv = bias ? bias[col] : 0.f;
#pragma unroll
                for (int r = 0; r < 4; ++r) {
                    int row = bm0 + wm + i * 16 + quad * 4 + r;
                    float val = acc[i][j][r];
                    if (bias) val = sigmoidf_(val + bv);
                    C[(size_t)row * 512 + col] = val;
                }
            }
    } else {
        // ---- index-score lower-triangle tiles, next-head As prefetched
        int b = gb - 320;
        int bq = (int)((sqrtf(8.0f * (float)b + 1.0f) - 1.0f) * 0.5f);
        while ((bq + 1) * (bq + 2) / 2 <= b) ++bq;
        while (bq * (bq + 1) / 2 > b) --bq;
        int bk = b - bq * (bq + 1) / 2;
        int q0 = bq * 64, k0 = bk * 64;
        int tx = tid & 15, ty = tid >> 4;
        int er = tid >> 4 /*unused*/;
        (void)er;
        float fin[4][4] = {};
        int r_[4], c4_[4];
#pragma unroll
        for (int i = 0; i < 4; ++i) {
            int e = tid + i * 256;
            r_[i] = e >> 4;
            c4_[i] = e & 15;
        }
        // stage Bs once ([k][n]) and As head 0 ([k][m])
#pragma unroll
        for (int i = 0; i < 4; ++i) {
            int r = r_[i], c4 = c4_[i];
            float4 bv = *(const float4*)(ki + (size_t)(k0 + r) * DI + c4 * 4);
            u.sc.Bs[c4 * 4 + 0][r] = bv.x;
            u.sc.Bs[c4 * 4 + 1][r] = bv.y;
            u.sc.Bs[c4 * 4 + 2][r] = bv.z;
            u.sc.Bs[c4 * 4 + 3][r] = bv.w;
            float4 av = *(const float4*)(qi + (size_t)(q0 + r) * (NI * DI) + c4 * 4);
            u.sc.As[c4 * 4 + 0][r] = av.x;
            u.sc.As[c4 * 4 + 1][r] = av.y;
            u.sc.As[c4 * 4 + 2][r] = av.z;
            u.sc.As[c4 * 4 + 3][r] = av.w;
        }
        __syncthreads();
#pragma unroll
        for (int h = 0; h < NI; ++h) {
            float4 pref[4];
            if (h < NI - 1) {
#pragma unroll
                for (int i = 0; i < 4; ++i)
                    pref[i] = *(const float4*)(qi + (size_t)(q0 + r_[i]) * (NI * DI) +
                                               (h + 1) * DI + c4_[i] * 4);
            }
            float raw[4][4] = {};
#pragma unroll 8
            for (int kk = 0; kk < 64; ++kk) {
                float4 a4 = *(const float4*)&u.sc.As[kk][ty * 4];
                float4 b4 = *(const float4*)&u.sc.Bs[kk][tx * 4];
                float a[4] = {a4.x, a4.y, a4.z, a4.w};
                float bb[4] = {b4.x, b4.y, b4.z, b4.w};
#pragma unroll
                for (int i = 0; i < 4; ++i)
#pragma unroll
                    for (int j = 0; j < 4; ++j) raw[i][j] += a[i] * bb[j];
            }
            float bh = idx_bias[h];
            float w4[4];
#pragma unroll
            for (int i = 0; i < 4; ++i) w4[i] = wsig[(q0 + ty * 4 + i) * NI + h];
#pragma unroll
            for (int i = 0; i < 4; ++i)
#pragma unroll
                for (int j = 0; j < 4; ++j)
                    fin[i][j] += sigmoidf_(raw[i][j] * 0.125f + bh) * w4[i];
            if (h < NI - 1) {
                __syncthreads();
#pragma unroll
                for (int i = 0; i < 4; ++i) {
                    int r = r_[i], c4 = c4_[i];
                    u.sc.As[c4 * 4 + 0][r] = pref[i].x;
                    u.sc.As[c4 * 4 + 1][r] = pref[i].y;
                    u.sc.As[c4 * 4 + 2][r] = pref[i].z;
                    u.sc.As[c4 * 4 + 3][r] = pref[i].w;
                }
                __syncthreads();
            }
        }
#pragma unroll
        for (int i = 0; i < 4; ++i) {
            int qq = q0 + ty * 4 + i;
#pragma unroll
            for (int j = 0; j < 4; ++j) {
                int kk = k0 + tx * 4 + j;
                unsigned key = 0;
                if (kk <= qq) {
                    unsigned uu = __float_as_uint(fin[i][j]);
                    key = (uu & 0x80000000u) ? ~uu : (uu | 0x80000000u);
                }
                keys[(size_t)qq * TT + kk] = key;
            }
        }
    }
}

// ---------------------------------------------------------------------------
// late: topk (blocks 0..2047) | post vmul+rope (2048..5119).
// ---------------------------------------------------------------------------
__global__ __launch_bounds__(256) void late_kernel(
    const unsigned* __restrict__ keys, int* __restrict__ indices,
    int* __restrict__ counts, const float* __restrict__ vb,
    const float* __restrict__ vgb, ushort* __restrict__ v16,
    float* __restrict__ q, const float* __restrict__ k,
    ushort* __restrict__ k16) {
    __shared__ unsigned ks_[TT];
    __shared__ unsigned hist[256];
    __shared__ unsigned wtot[4];
    __shared__ unsigned s_prefix, s_above;
    __shared__ int eqlist[256];
    __shared__ unsigned eqcount, outpos;
    int gb = blockIdx.x;
    int tid = threadIdx.x;
    if (gb >= 2048) {
        int b = gb - 2048;
        if (b < 1024) {
            int e = b * 256 + tid;
            float4 v = ((const float4*)vb)[e];
            float4 g = ((const float4*)vgb)[e];
            ushort4 r;
            r.x = f2bf(v.x * g.x); r.y = f2bf(v.y * g.y);
            r.z = f2bf(v.z * g.z); r.w = f2bf(v.w * g.w);
            ((ushort4*)v16)[e] = r;
        } else {
            int i = (b - 1024) * 256 + tid;
            int j = i & 31;
            int h = (i >> 5) & 7;
            int t = i >> 8;
            const float L2_10000 = 13.287712379549449f;
            float inv = exp2f(-(float)j * (1.0f / 32.0f) * L2_10000);
            float ang = (float)t * inv;
            float c = cosf(ang), s = sinf(ang);
            int base = t * DD + h * DH;
            float q1 = q[base + j], q2 = q[base + j + 32];
            q[base + j] = q1 * c - q2 * s;
            q[base + j + 32] = q2 * c + q1 * s;
            float k1 = k[base + j], k2 = k[base + j + 32];
            k16[base + j] = f2bf(k1 * c - k2 * s);
            k16[base + j + 32] = f2bf(k2 * c + k1 * s);
        }
        return;
    }
    int qrow = gb;
    int lane = tid & 63, wv = tid >> 6;
    int n = qrow + 1;
    if (n <= KSEL) {
        if (tid < n) indices[qrow * KSEL + tid] = tid;
        if (tid == 0) counts[qrow] = n;
        return;
    }
    if (tid == 0) counts[qrow] = KSEL;
    const unsigned* krow = keys + (size_t)qrow * TT;
    for (int k_ = tid; k_ < n; k_ += 256) ks_[k_] = krow[k_];
    __syncthreads();
    unsigned prefix = 0;
    int remaining = KSEL;
    for (int level = 24; level >= 0; level -= 8) {
        hist[tid] = 0;
        __syncthreads();
        for (int k_ = tid; k_ < n; k_ += 256) {
            unsigned key = ks_[k_];
            bool match = ((unsigned long long)key >> (level + 8)) == (unsigned long long)prefix;
            if (match) atomicAdd(&hist[(key >> level) & 255], 1u);
        }
        __syncthreads();
        unsigned v = hist[tid];
#pragma unroll
        for (int off = 1; off < 64; off <<= 1) {
            unsigned t = __shfl_down(v, off);
            if (lane + off < 64) v += t;
        }
        if (lane == 0) wtot[wv] = v;
        __syncthreads();
        unsigned add = 0;
#pragma unroll
        for (int uu = 1; uu < 4; ++uu)
            if (wv + uu < 4) add += wtot[wv + uu];
        v += add;
        hist[tid] = v;
        __syncthreads();
        if (hist[tid] >= (unsigned)remaining &&
            (tid == 255 || hist[tid + 1] < (unsigned)remaining)) {
            s_prefix = (prefix << 8) | (unsigned)tid;
            s_above = (tid == 255) ? 0u : hist[tid + 1];
        }
        __syncthreads();
        prefix = s_prefix;
        remaining -= (int)s_above;
        __syncthreads();
    }
    if (tid == 0) { eqcount = 0; outpos = 0; }
    __syncthreads();
    int outbase = qrow * KSEL;
    for (int k_ = tid; k_ < n; k_ += 256) {
        unsigned key = ks_[k_];
        if (key > prefix) {
            unsigned p = atomicAdd(&outpos, 1u);
            indices[outbase + p] = k_;
        } else if (key == prefix) {
            unsigned e = atomicAdd(&eqcount, 1u);
            if (e < 256) eqlist[e] = k_;
        }
    }
    __syncthreads();
    if (tid == 0) {
        int r = remaining;
        int E = (int)eqcount;
        if (E > 256) E = 256;
        if (r > E) r = E;
        int pos = (int)outpos;
        for (int t = 0; t < r; ++t) {
            int best = 0x7fffffff, bj = -1;
            for (int j = 0; j < E; ++j) {
                int vv = eqlist[j];
                if (vv < best) { best = vv; bj = j; }
            }
            eqlist[bj] = 0x7fffffff;
            indices[outbase + pos + t] = best;
        }
    }
}

// ---------------------------------------------------------------------------
// Sparse attention: grid (TT,2), wave w owns head blockIdx.y*4+w.
// ---------------------------------------------------------------------------
__global__ __launch_bounds__(256) void attn_kernel(
    const float* __restrict__ q, const ushort* __restrict__ k16,
    const ushort* __restrict__ v16, const float* __restrict__ og,
    const int* __restrict__ indices, const int* __restrict__ counts,
    ushort* __restrict__ out) {
    __shared__ int idx[KSEL];
    __shared__ ushort kw[4][32 * 68];
    __shared__ float qv[4][DH];
    __shared__ float pw[4][KSEL];
    int qrow = blockIdx.x;
    int tid = threadIdx.x;
    int lane = tid & 63, w = tid >> 6;
    int cnt = counts[qrow];
    if (tid < KSEL) idx[tid] = (tid < cnt) ? indices[qrow * KSEL + tid] : 0;
    __syncthreads();
    ushort* kws = kw[w];
    float* qvs = qv[w];
    float* pps = pw[w];
    int h = blockIdx.y * 4 + w;
    int hb = h * DH;
    qvs[lane] = q[qrow * DD + hb + lane];
    int j2 = lane & 31, half = lane >> 5;
    int r4 = lane >> 4, cs = (lane & 15) * 4;
    float sc[4];
#pragma unroll
    for (int c = 0; c < 4; ++c) {
#pragma unroll
        for (int it = 0; it < 8; ++it) {
            int r = it * 4 + r4;
            int row = idx[c * 32 + r];
            *(ushort4*)&kws[r * 68 + cs] =
                *(const ushort4*)(k16 + (size_t)row * DD + hb + cs);
        }
        float acc0 = 0.f, acc1 = 0.f;
        const ushort* kr = kws + j2 * 68 + half * 32;
        const float* qr = qvs + half * 32;
#pragma unroll
        for (int dd = 0; dd < 8; dd += 2) {
            ushort4 ka = *(const ushort4*)&kr[dd * 4];
            ushort4 kb_ = *(const ushort4*)&kr[dd * 4 + 4];
            acc0 += bf2f(ka.x) * qr[dd * 4 + 0] + bf2f(ka.y) * qr[dd * 4 + 1] +
                    bf2f(ka.z) * qr[dd * 4 + 2] + bf2f(ka.w) * qr[dd * 4 + 3];
            acc1 += bf2f(kb_.x) * qr[dd * 4 + 4] + bf2f(kb_.y) * qr[dd * 4 + 5] +
                    bf2f(kb_.z) * qr[dd * 4 + 6] + bf2f(kb_.w) * qr[dd * 4 + 7];
        }
        float acc = acc0 + acc1;
        acc += __shfl_xor(acc, 32);
        int j = c * 32 + j2;
        sc[c] = (j < cnt) ? acc * 0.125f : -1e30f;
    }
    float m = fmaxf(fmaxf(sc[0], sc[1]), fmaxf(sc[2], sc[3]));
#pragma unroll
    for (int off = 16; off; off >>= 1) m = fmaxf(m, __shfl_xor(m, off));
    float pc[4], sum = 0.f;
#pragma unroll
    for (int c = 0; c < 4; ++c) {
        pc[c] = __expf(sc[c] - m);
        sum += pc[c];
    }
#pragma unroll
    for (int off = 16; off; off >>= 1) sum += __shfl_xor(sum, off);
    float inv = 1.0f / sum;
    if (half == 0) {
#pragma unroll
        for (int c = 0; c < 4; ++c) pps[c * 32 + j2] = pc[c] * inv;
    }
    int dgroup = lane & 15, g = lane >> 4;
    int db = dgroup * 4;
    float a0 = 0.f, a1 = 0.f, a2 = 0.f, a3 = 0.f;
    float b0 = 0.f, b1 = 0.f, b2 = 0.f, b3 = 0.f;
#pragma unroll 8
    for (int t = 0; t < 32; t += 2) {
        int jA = g + 4 * t;
        int jB = g + 4 * t + 4;
        int rowA = idx[jA];
        int rowB = idx[jB];
        float pA = pps[jA], pB = pps[jB];
        ushort4 va = *(const ushort4*)(v16 + (size_t)rowA * DD + hb + db);
        ushort4 vb = *(const ushort4*)(v16 + (size_t)rowB * DD + hb + db);
        a0 += pA * bf2f(va.x); a1 += pA * bf2f(va.y);
        a2 += pA * bf2f(va.z); a3 += pA * bf2f(va.w);
        b0 += pB * bf2f(vb.x); b1 += pB * bf2f(vb.y);
        b2 += pB * bf2f(vb.z); b3 += pB * bf2f(vb.w);
    }
    a0 += b0; a1 += b1; a2 += b2; a3 += b3;
    a0 += __shfl_xor(a0, 16); a0 += __shfl_xor(a0, 32);
    a1 += __shfl_xor(a1, 16); a1 += __shfl_xor(a1, 32);
    a2 += __shfl_xor(a2, 16); a2 += __shfl_xor(a2, 32);
    a3 += __shfl_xor(a3, 16); a3 += __shfl_xor(a3, 32);
    if (g == 0) {
        int o = qrow * DD + hb + db;
        float4 gg = *(const float4*)(og + o);
        ushort4 r;
        r.x = f2bf(a0 * gg.x);
        r.y = f2bf(a1 * gg.y);
        r.z = f2bf(a2 * gg.z);
        r.w = f2bf(a3 * gg.w);
        *(ushort4*)(out + o) = r;
    }
}

// ---------------------------------------------------------------------------
// Wo MFMA GEMM, 64x64 tile (4 waves x 2x2 fragments) -> 256 blocks.
// ---------------------------------------------------------------------------
__global__ __launch_bounds__(256) void wo64_kernel(
    const ushort* __restrict__ A, const ushort* __restrict__ BT,
    float* __restrict__ C) {
    __shared__ __align__(16) ushort As[64][32];
    __shared__ __align__(16) ushort Bs[64][32];
    const int K = 512;
    int tid = threadIdx.x;
    int bm0 = blockIdx.y * 64, bn0 = blockIdx.x * 64;
    int w = tid >> 6, lane = tid & 63;
    int wm = (w >> 1) * 32, wn = (w & 1) * 32;
    int quad = lane >> 4, mr = lane & 15;
    f32x4 acc[2][2];
#pragma unroll
    for (int i = 0; i < 2; ++i)
#pragma unroll
        for (int j = 0; j < 2; ++j)
#pragma unroll
            for (int r = 0; r < 4; ++r) acc[i][j][r] = 0.f;
    int rs = tid >> 2, cs = (tid & 3) * 8;
    for (int k0 = 0; k0 < K; k0 += 32) {
        *(float4*)&As[rs][cs] = *(const float4*)(A + (size_t)(bm0 + rs) * K + k0 + cs);
        *(float4*)&Bs[rs][cs] = *(const float4*)(BT + (size_t)(bn0 + rs) * K + k0 + cs);
        __syncthreads();
        bf16x8 af[2], bfv[2];
#pragma unroll
        for (int i = 0; i < 2; ++i)
            af[i] = *(const bf16x8*)&As[wm + i * 16 + mr][quad * 8];
#pragma unroll
        for (int j = 0; j < 2; ++j)
            bfv[j] = *(const bf16x8*)&Bs[wn + j * 16 + mr][quad * 8];
#pragma unroll
        for (int i = 0; i < 2; ++i)
#pragma unroll
            for (int j = 0; j < 2; ++j)
                acc[i][j] = __builtin_amdgcn_mfma_f32_16x16x32_bf16(
                    af[i], bfv[j], acc[i][j], 0, 0, 0);
        __syncthreads();
    }
#pragma unroll
    for (int i = 0; i < 2; ++i)
#pragma unroll
        for (int j = 0; j < 2; ++j) {
            int col = bn0 + wn + j * 16 + mr;
#pragma unroll
            for (int r = 0; r < 4; ++r) {
                int row = bm0 + wm + i * 16 + quad * 4 + r;
                C[(size_t)row * 512 + col] = acc[i][j][r];
            }
        }
}

// ---------------------------------------------------------------------------
extern "C" void kernel_launch(void* const* d_in, const int* in_sizes, int n_in,
                              void* d_out, int out_size, void* d_ws, size_t ws_size,
                              hipStream_t stream) {
    const float* x = (const float*)d_in[0];
    const float* Wq = (const float*)d_in[1];
    const float* Wk = (const float*)d_in[2];
    const float* Wv = (const float*)d_in[3];
    const float* Wo = (const float*)d_in[4];
    const float* Wiq = (const float*)d_in[5];
    const float* Wik = (const float*)d_in[6];
    const float* Wiw = (const float*)d_in[7];
    const float* biw = (const float*)d_in[8];
    const float* idx_bias = (const float*)d_in[9];
    const float* Wvg = (const float*)d_in[10];
    const float* bvg = (const float*)d_in[11];
    const float* Wog = (const float*)d_in[12];
    const float* bog = (const float*)d_in[13];
    float* out = (float*)d_out;
    char* base = (char*)d_ws;

    float* qb = (float*)(base + 0);
    float* kb = (float*)(base + (4ull << 20));
    float* vb = (float*)(base + (8ull << 20));
    ushort* ab_bf = (ushort*)(base + (8ull << 20));
    float* vgb = (float*)(base + (12ull << 20));
    float* ogb = (float*)(base + (16ull << 20));
    float* qib = (float*)(base + (20ull << 20));
    float* kib = (float*)(base + (22ull << 20));
    float* wsb = (float*)(base + (22ull << 20) + (512u << 10));
    ushort* xb = (ushort*)(base + (23ull << 20));
    int* idxb = (int*)(base + (23ull << 20));
    int* cntb = (int*)(base + (24ull << 20));
    ushort* wtb = (ushort*)(base + (25ull << 20));
    ushort* kb16 = (ushort*)(base + (28ull << 20));
    ushort* vb16 = (ushort*)(base + (30ull << 20));
    unsigned* keysb = (unsigned*)(base + (32ull << 20));

    dim3 blk(256);
    hipMemsetAsync(qib, 0, (size_t)(TT * NI * DI + TT * DI) * sizeof(float), stream);
    prep_kernel<<<3392, blk, 0, stream>>>(x, Wq, Wk, Wv, Wvg, Wog, Wo, Wiq, Wik,
                                          Wiw, biw, xb, wtb, qib, kib, wsb);
    mid_kernel<<<848, blk, 0, stream>>>(xb, wtb, qb, kb, vb, vgb, ogb, bvg, bog,
                                        qib, kib, wsb, idx_bias, keysb);
    late_kernel<<<5120, blk, 0, stream>>>(keysb, idxb, cntb, vb, vgb, vb16, qb,
                                          kb, kb16);
    attn_kernel<<<dim3(TT, 2), blk, 0, stream>>>(qb, kb16, vb16, ogb, idxb, cntb, ab_bf);
    wo64_kernel<<<dim3(8, 32), blk, 0, stream>>>(ab_bf, wtb + (size_t)5 * 512 * 512, out);
}